// Round 4
// baseline (334.030 us; speedup 1.0000x reference)
//
#include <hip/hip_runtime.h>

// DEPTree on gfx950 — Round 4: single mega-kernel with device grid barriers.
// Theory: ~8us per-dispatch overhead x 13 dispatches dominated round 3's 201us.
// Now: 1 tiny memset + 1 kernel with 12 phases / 11 hierarchical barriers.
// K=4, LEVELS=8, N=21845, D=128, NUM_POS=18, NUM_DEP=46

#define DD 128
#define NN 21845
#define NPOS 18
#define NDEP 46
#define NCH 21844
#define NBUCKET 340
#define GRID 432          // 27 groups x 16 blocks
#define NBAR 12

typedef __attribute__((ext_vector_type(8))) short short8;
typedef __attribute__((ext_vector_type(4))) float f32x4;

__device__ __forceinline__ unsigned short f2bf(float f) {
    union { float f; unsigned int u; } v; v.f = f;
    unsigned int r = v.u + 0x7fffu + ((v.u >> 16) & 1u);   // RNE
    return (unsigned short)(r >> 16);
}
__device__ __forceinline__ float bf2f(unsigned short s) {
    union { unsigned int u; float f; } v; v.u = ((unsigned int)s) << 16;
    return v.f;
}

__device__ __forceinline__ void decode_child(int j, const int* __restrict__ dep_ids,
                                             int& l, int& c, int& b) {
    int base = 0, sz = 4;
    l = 0;
    while (j >= base + sz) { base += sz; sz <<= 2; ++l; }
    c = j - base;
    int did = dep_ids[base + 1 + c];          // ls[l+1] = base+1
    b = NPOS + l * NDEP + did;
}

// hierarchical grid barrier: 27 groups of 16 blocks; state pre-zeroed by memset.
__device__ __forceinline__ void gridbar(int* c0, int* c1, int* gen, int idx) {
    __syncthreads();
    if (threadIdx.x == 0) {
        __threadfence();                              // release (agent scope)
        int g = blockIdx.x >> 4;
        if (atomicAdd(&c0[(idx * 27 + g) * 16], 1) == 15) {
            if (atomicAdd(&c1[idx * 16], 1) == 26) {
                __hip_atomic_store(gen, idx + 1, __ATOMIC_RELEASE,
                                   __HIP_MEMORY_SCOPE_AGENT);
            }
        }
        while (__hip_atomic_load(gen, __ATOMIC_RELAXED,
                                 __HIP_MEMORY_SCOPE_AGENT) < idx + 1)
            __builtin_amdgcn_s_sleep(4);
        __threadfence();                              // acquire
    }
    __syncthreads();
}

// one 64-row x 128-col MFMA tile; 4 waves x (16 rows, 8 n-tiles), K=128
// MODE 0: A = bf16(emb[perm[r]]) ; MODE 1: A = xb[perm[r]] ;
// MODE 2: A = max(xb[c], uprev[4c+j])
template <int MODE>
__device__ __forceinline__ void gemm_tile(
        int2 e, const int* __restrict__ perm, const unsigned short* __restrict__ Wt,
        const float* __restrict__ bias, const float* __restrict__ embf,
        const unsigned short* __restrict__ xb, const unsigned short* __restrict__ uprev,
        unsigned short* __restrict__ outr) {
    int bucket = e.x & 255;
    int rows = e.x >> 8;
    int rowstart = e.y;
    int lane = threadIdx.x & 63;
    int w = threadIdx.x >> 6;
    int lr = lane & 15;
    int kk = (lane >> 4) * 8;
    const short8 zero8 = {0, 0, 0, 0, 0, 0, 0, 0};

    int m_a = w * 16 + lr;
    bool valid_a = m_a < rows;
    int rid_a = valid_a ? perm[rowstart + m_a] : 0;

    short8 afr[4];
    if (MODE == 0) {
        const float* ar = embf + (size_t)rid_a * DD + kk;
#pragma unroll
        for (int s = 0; s < 4; ++s) {
            float4 lo = *(const float4*)(ar + s * 32);
            float4 hi = *(const float4*)(ar + s * 32 + 4);
            short8 a;
            a[0] = (short)f2bf(lo.x); a[1] = (short)f2bf(lo.y);
            a[2] = (short)f2bf(lo.z); a[3] = (short)f2bf(lo.w);
            a[4] = (short)f2bf(hi.x); a[5] = (short)f2bf(hi.y);
            a[6] = (short)f2bf(hi.z); a[7] = (short)f2bf(hi.w);
            afr[s] = valid_a ? a : zero8;
        }
    } else if (MODE == 1) {
        const unsigned short* ar = xb + (size_t)rid_a * DD + kk;
#pragma unroll
        for (int s = 0; s < 4; ++s)
            afr[s] = valid_a ? *(const short8*)(ar + s * 32) : zero8;
    } else {
        const unsigned short* xr = xb + (size_t)rid_a * DD + kk;
        const unsigned short* ur = uprev + (size_t)(4 * rid_a) * DD + kk;
#pragma unroll
        for (int s = 0; s < 4; ++s) {
            short8 a = *(const short8*)(xr + s * 32);
#pragma unroll
            for (int j = 0; j < 4; ++j) {
                short8 u = *(const short8*)(ur + j * DD + s * 32);
#pragma unroll
                for (int q = 0; q < 8; ++q)
                    if ((unsigned short)u[q] > (unsigned short)a[q]) a[q] = u[q];
            }
            afr[s] = valid_a ? a : zero8;
        }
    }

    f32x4 acc[8];
#pragma unroll
    for (int t = 0; t < 8; ++t) acc[t] = (f32x4){0.f, 0.f, 0.f, 0.f};

    const unsigned short* Wb = Wt + (size_t)bucket * DD * DD;
#pragma unroll
    for (int s = 0; s < 4; ++s) {
        short8 bfr[8];
#pragma unroll
        for (int t = 0; t < 8; ++t)
            bfr[t] = *(const short8*)(Wb + (size_t)(t * 16 + lr) * DD + s * 32 + kk);
#pragma unroll
        for (int t = 0; t < 8; ++t)
            acc[t] = __builtin_amdgcn_mfma_f32_16x16x32_bf16(afr[s], bfr[t], acc[t], 0, 0, 0);
    }

    int rq[4]; bool vq[4];
#pragma unroll
    for (int q = 0; q < 4; ++q) {
        int m = w * 16 + (lane >> 4) * 4 + q;
        vq[q] = m < rows;
        rq[q] = vq[q] ? perm[rowstart + m] : 0;
    }
    const float* bb = bias + bucket * DD;
#pragma unroll
    for (int t = 0; t < 8; ++t) {
        int col = t * 16 + lr;
        float bv = bb[col];
#pragma unroll
        for (int q = 0; q < 4; ++q) {
            if (vq[q]) {
                float v = fmaxf(acc[t][q] + bv, 0.f);
                outr[(size_t)rq[q] * DD + col] = f2bf(v);
            }
        }
    }
}

__global__ __launch_bounds__(256, 2) void mega_kernel(
        const float* __restrict__ emb, const int* __restrict__ pos_ids,
        const int* __restrict__ dep_ids, const float* __restrict__ posW,
        const float* __restrict__ pos_b, const float* __restrict__ depW,
        const float* __restrict__ dep_b, float* __restrict__ out,
        int* __restrict__ cnt, int* __restrict__ c0, int* __restrict__ c1,
        int* __restrict__ gen, int* __restrict__ cur, int* __restrict__ ntiles,
        int* __restrict__ perm_pos, int* __restrict__ perm_dep,
        int2* __restrict__ tbl1, int2* __restrict__ tblL,
        unsigned short* __restrict__ Wt, unsigned short* __restrict__ xbf,
        unsigned short* __restrict__ uA, unsigned short* __restrict__ uB) {
    __shared__ char smem[9232];
    int bid = blockIdx.x;
    int tid = threadIdx.x;

    // ---- P0: convert W (blocks 0..255) + histogram (blocks 256..426) ----
    if (bid < 256) {
        unsigned short (*lds)[72] = (unsigned short (*)[72])smem;
        int mat = bid >> 2;
        int tile = bid & 3;
        int tk = (tile >> 1) * 64, tn = (tile & 1) * 64;
        const float* W = (mat < NPOS) ? (posW + (size_t)mat * DD * DD)
                                      : (depW + (size_t)(mat - NPOS) * DD * DD);
        unsigned short* O = Wt + (size_t)mat * DD * DD;
        int tx = tid & 63, ty = tid >> 6;
#pragma unroll
        for (int i = 0; i < 16; ++i) {
            int r = ty + i * 4;
            lds[tx][r] = f2bf(W[(size_t)(tk + r) * DD + tn + tx]);
        }
        __syncthreads();
#pragma unroll
        for (int i = 0; i < 16; ++i) {
            int r = ty + i * 4;
            O[(size_t)(tn + r) * DD + tk + tx] = lds[r][tx];
        }
    } else if (bid < 427) {
        int* h = (int*)smem;
        for (int i = tid; i < NBUCKET; i += 256) h[i] = 0;
        __syncthreads();
        int g = (bid - 256) * 256 + tid;
        if (g < NN) {
            atomicAdd(&h[pos_ids[g]], 1);
        } else if (g < NN + NCH) {
            int l, c, b;
            decode_child(g - NN, dep_ids, l, c, b);
            atomicAdd(&h[b], 1);
        }
        __syncthreads();
        for (int i = tid; i < NBUCKET; i += 256) {
            int v = h[i];
            if (v) atomicAdd(&cnt[i], v);
        }
    }
    gridbar(c0, c1, gen, 0);

    // ---- P1: parallel scan, blocks 0..7 (wave 0), group 0=pos, 1+l=dep level l
    if (bid < 8 && tid < 64) {
        int grp = bid;
        int NB = (grp == 0) ? NPOS : NDEP;
        int cntoff = (grp == 0) ? 0 : NPOS + (grp - 1) * NDEP;
        int base = 0;
        if (grp > 0) { int l = grp - 1; base = ((1 << (2 * l + 2)) - 4) / 3; }
        int2* tb = (grp == 0) ? tbl1 : tblL + (grp - 1) * 302;
        int lane = tid;
        int c = (lane < NB) ? cnt[cntoff + lane] : 0;
        int t = (c + 63) >> 6;
        int pi = c, qi = t;
#pragma unroll
        for (int off = 1; off < 64; off <<= 1) {
            int a = __shfl_up(pi, off);
            int b2 = __shfl_up(qi, off);
            if (lane >= off) { pi += a; qi += b2; }
        }
        int pe = pi - c, qe = qi - t;
        if (lane < NB) {
            cur[cntoff + lane] = base + pe;
            for (int k = 0; k < t; ++k) {
                int rr = min(64, c - (k << 6));
                int2 ent; ent.x = lane | (rr << 8); ent.y = base + pe + (k << 6);
                tb[qe + k] = ent;
            }
            if (lane == NB - 1) ntiles[grp] = qi;
        }
    }
    gridbar(c0, c1, gen, 1);

    // ---- P2: scatter (blocks 0..170) ----
    if (bid < 171) {
        int* h = (int*)smem;
        int* basep = h + NBUCKET;
        for (int i = tid; i < NBUCKET; i += 256) h[i] = 0;
        __syncthreads();
        int g = bid * 256 + tid;
        int b = -1, payload = 0;
        if (g < NN) {
            b = pos_ids[g]; payload = g;
        } else if (g < NN + NCH) {
            int l, c;
            decode_child(g - NN, dep_ids, l, c, b);
            payload = c;
        }
        int local = 0;
        if (b >= 0) local = atomicAdd(&h[b], 1);
        __syncthreads();
        for (int i = tid; i < NBUCKET; i += 256) {
            int v = h[i];
            if (v) basep[i] = atomicAdd(&cur[i], v);
        }
        __syncthreads();
        if (b >= 0) {
            int idx = basep[b] + local;
            if (b < NPOS) perm_pos[idx] = payload;
            else perm_dep[idx] = payload;
        }
    }
    gridbar(c0, c1, gen, 2);

    // ---- P3: stage1 GEMM (<=360 tiles) ----
    if (bid < ntiles[0])
        gemm_tile<0>(tbl1[bid], perm_pos, Wt, pos_b, emb, nullptr, nullptr, xbf);
    gridbar(c0, c1, gen, 3);

    const unsigned short* Wtd = Wt + (size_t)NPOS * DD * DD;
    // ---- P4: level 6 (<=302 tiles): A = x leaf rows ----
    if (bid < ntiles[7])
        gemm_tile<1>(tblL[6 * 302 + bid], perm_dep, Wtd, dep_b, nullptr,
                     xbf + (size_t)5461 * DD, nullptr, uA);
    gridbar(c0, c1, gen, 4);

    // ---- P5..P10: levels 5..0 ----
    unsigned short* uin = uA;
    unsigned short* uout = uB;
    int baridx = 5;
    for (int l = 5; l >= 0; --l) {
        int lsc = ((1 << (2 * l + 2)) - 1) / 3;   // ls[l+1]
        if (bid < ntiles[1 + l])
            gemm_tile<2>(tblL[l * 302 + bid], perm_dep, Wtd, dep_b, nullptr,
                         xbf + (size_t)lsc * DD, uin, uout);
        gridbar(c0, c1, gen, baridx++);
        unsigned short* tswap = uin; uin = uout; uout = tswap;
    }

    // ---- P11: final (block 0): out = max(x[0], u_l0 rows 0..3) ----
    if (bid == 0 && tid < DD) {
        unsigned short m = xbf[tid];
#pragma unroll
        for (int j = 0; j < 4; ++j) {
            unsigned short u = uin[j * DD + tid];
            if (u > m) m = u;
        }
        out[tid] = bf2f(m);
    }
}

extern "C" void kernel_launch(void* const* d_in, const int* in_sizes, int n_in,
                              void* d_out, int out_size, void* d_ws, size_t ws_size,
                              hipStream_t stream) {
    const float* emb     = (const float*)d_in[0];
    const int*   pos_ids = (const int*)d_in[1];
    const int*   dep_ids = (const int*)d_in[2];
    const float* pos_W   = (const float*)d_in[3];
    const float* pos_b   = (const float*)d_in[4];
    const float* dep_W   = (const float*)d_in[5];
    const float* dep_b   = (const float*)d_in[6];
    float* out = (float*)d_out;

    char* p = (char*)d_ws;
    auto alloc = [&](size_t bytes) {
        char* r = p; p += (bytes + 255) & ~(size_t)255; return r;
    };
    // meta block (memset to 0 each call): cnt | c0 | c1 | gen
    int* meta = (int*)alloc((340 + NBAR * 27 * 16 + NBAR * 16 + 1) * 4);
    int* cnt = meta;
    int* c0  = meta + 340;
    int* c1  = c0 + NBAR * 27 * 16;
    int* gen = c1 + NBAR * 16;
    size_t meta_bytes = (size_t)(340 + NBAR * 27 * 16 + NBAR * 16 + 1) * 4;

    int*  cur      = (int*)alloc(NBUCKET * 4);
    int*  ntiles   = (int*)alloc(8 * 4);
    int*  perm_pos = (int*)alloc((size_t)NN * 4);
    int*  perm_dep = (int*)alloc((size_t)NCH * 4);
    int2* tbl1     = (int2*)alloc(360 * 8);
    int2* tblL     = (int2*)alloc(7 * 302 * 8);
    unsigned short* Wt  = (unsigned short*)alloc((size_t)64 * DD * DD * 2);
    unsigned short* xbf = (unsigned short*)alloc((size_t)NN * DD * 2);
    unsigned short* uA  = (unsigned short*)alloc((size_t)16384 * DD * 2);
    unsigned short* uB  = (unsigned short*)alloc((size_t)4096 * DD * 2);

    hipMemsetAsync(meta, 0, meta_bytes, stream);
    mega_kernel<<<GRID, 256, 0, stream>>>(emb, pos_ids, dep_ids, pos_W, pos_b,
                                          dep_W, dep_b, out, cnt, c0, c1, gen,
                                          cur, ntiles, perm_pos, perm_dep,
                                          tbl1, tblL, Wt, xbf, uA, uB);
}

// Round 5
// 323.583 us; speedup vs baseline: 1.0323x; 1.0323x over previous
//
#include <hip/hip_runtime.h>

// DEPTree on gfx950 — Round 5: mega-kernel with LEADER-based XCD barriers.
// Round-4 post-mortem: 432 blocks x 2 __threadfence per barrier = ~20us/barrier
// (L2 wb/inv storms). Now only 1 block per XCD fences (8 total), data buffers
// are written-once (7 distinct u buffers), scan phase folded into scatter,
// final folded into the L0 phase. 9 barriers.

#define DD 128
#define NN 21845
#define NPOS 18
#define NDEP 46
#define NCH 21844
#define NBUCKET 340
#define GRID 432
#define NBAR 9
#define NHB 171

typedef __attribute__((ext_vector_type(8))) short short8;
typedef __attribute__((ext_vector_type(4))) float f32x4;
#define AGENT __HIP_MEMORY_SCOPE_AGENT

static __device__ __forceinline__ int aload(int* p) {
    return __hip_atomic_load(p, __ATOMIC_RELAXED, AGENT);
}
static __device__ __forceinline__ void astore(int* p, int v) {
    __hip_atomic_store(p, v, __ATOMIC_RELAXED, AGENT);
}
static __device__ __forceinline__ int aadd(int* p, int v) {
    return __hip_atomic_fetch_add(p, v, __ATOMIC_RELAXED, AGENT);
}

__device__ __forceinline__ unsigned short f2bf(float f) {
    union { float f; unsigned int u; } v; v.f = f;
    unsigned int r = v.u + 0x7fffu + ((v.u >> 16) & 1u);   // RNE
    return (unsigned short)(r >> 16);
}
__device__ __forceinline__ float bf2f(unsigned short s) {
    union { unsigned int u; float f; } v; v.u = ((unsigned int)s) << 16;
    return v.f;
}

__device__ __forceinline__ void decode_child(int j, const int* __restrict__ dep_ids,
                                             int& l, int& c, int& b) {
    int base = 0, sz = 4;
    l = 0;
    while (j >= base + sz) { base += sz; sz <<= 2; ++l; }
    c = j - base;
    int did = dep_ids[base + 1 + c];          // ls[l+1] = base+1
    b = NPOS + l * NDEP + did;
}

// ---- leader-fence grid barrier ----
// meta layout (ints): claim[NBAR*8*32] | arrive[NBAR*32] | ready[NBAR*32]
//                     | go[NBAR*32] | nxcd[32]
__device__ __forceinline__ void gridbar(int* meta, int idx) {
    __syncthreads();   // compiler drains vmcnt/lgkm for all waves before barrier
    if (threadIdx.x == 0) {
        int* claim  = meta;
        int* arrive = meta + NBAR * 8 * 32;
        int* ready  = arrive + NBAR * 32;
        int* go     = ready + NBAR * 32;
        int* nxcd   = go + NBAR * 32;
        asm volatile("s_waitcnt vmcnt(0) lgkmcnt(0)" ::: "memory");
        int xcd;
        asm volatile("s_getreg_b32 %0, hwreg(HW_REG_XCC_ID)" : "=s"(xcd));
        xcd &= 7;
        bool leader = (aadd(&claim[(idx * 8 + xcd) * 32], 1) == 0);
        if (idx == 0 && leader) aadd(nxcd, 1);
        aadd(&arrive[idx * 32], 1);
        if (leader) {
            while (aload(&arrive[idx * 32]) < GRID) __builtin_amdgcn_s_sleep(2);
            int nx = aload(nxcd);
            __threadfence();                        // wb+inv THIS XCD's L2
            asm volatile("s_waitcnt vmcnt(0)" ::: "memory");
            int r = aadd(&ready[idx * 32], 1) + 1;
            if (r == nx) astore(&go[idx * 32], 1);
            else while (aload(&go[idx * 32]) == 0) __builtin_amdgcn_s_sleep(2);
        } else {
            while (aload(&go[idx * 32]) == 0) __builtin_amdgcn_s_sleep(2);
        }
    }
    __syncthreads();
}

// one 64-row x 128-col MFMA tile; 4 waves x (16 rows, 8 n-tiles), K=128
template <int MODE>
__device__ __forceinline__ void gemm_tile(
        int2 e, const int* __restrict__ perm, const unsigned short* __restrict__ Wt,
        const float* __restrict__ bias, const float* __restrict__ embf,
        const unsigned short* __restrict__ xb, const unsigned short* __restrict__ uprev,
        unsigned short* __restrict__ outr) {
    int bucket = e.x & 255;
    int rows = e.x >> 8;
    int rowstart = e.y;
    int lane = threadIdx.x & 63;
    int w = threadIdx.x >> 6;
    int lr = lane & 15;
    int kk = (lane >> 4) * 8;
    const short8 zero8 = {0, 0, 0, 0, 0, 0, 0, 0};

    int m_a = w * 16 + lr;
    bool valid_a = m_a < rows;
    int rid_a = valid_a ? perm[rowstart + m_a] : 0;

    short8 afr[4];
    if (MODE == 0) {
        const float* ar = embf + (size_t)rid_a * DD + kk;
#pragma unroll
        for (int s = 0; s < 4; ++s) {
            float4 lo = *(const float4*)(ar + s * 32);
            float4 hi = *(const float4*)(ar + s * 32 + 4);
            short8 a;
            a[0] = (short)f2bf(lo.x); a[1] = (short)f2bf(lo.y);
            a[2] = (short)f2bf(lo.z); a[3] = (short)f2bf(lo.w);
            a[4] = (short)f2bf(hi.x); a[5] = (short)f2bf(hi.y);
            a[6] = (short)f2bf(hi.z); a[7] = (short)f2bf(hi.w);
            afr[s] = valid_a ? a : zero8;
        }
    } else if (MODE == 1) {
        const unsigned short* ar = xb + (size_t)rid_a * DD + kk;
#pragma unroll
        for (int s = 0; s < 4; ++s)
            afr[s] = valid_a ? *(const short8*)(ar + s * 32) : zero8;
    } else {
        const unsigned short* xr = xb + (size_t)rid_a * DD + kk;
        const unsigned short* ur = uprev + (size_t)(4 * rid_a) * DD + kk;
#pragma unroll
        for (int s = 0; s < 4; ++s) {
            short8 a = *(const short8*)(xr + s * 32);
#pragma unroll
            for (int j = 0; j < 4; ++j) {
                short8 u = *(const short8*)(ur + j * DD + s * 32);
#pragma unroll
                for (int q = 0; q < 8; ++q)
                    if ((unsigned short)u[q] > (unsigned short)a[q]) a[q] = u[q];
            }
            afr[s] = valid_a ? a : zero8;
        }
    }

    f32x4 acc[8];
#pragma unroll
    for (int t = 0; t < 8; ++t) acc[t] = (f32x4){0.f, 0.f, 0.f, 0.f};

    const unsigned short* Wb = Wt + (size_t)bucket * DD * DD;
#pragma unroll
    for (int s = 0; s < 4; ++s) {
        short8 bfr[8];
#pragma unroll
        for (int t = 0; t < 8; ++t)
            bfr[t] = *(const short8*)(Wb + (size_t)(t * 16 + lr) * DD + s * 32 + kk);
#pragma unroll
        for (int t = 0; t < 8; ++t)
            acc[t] = __builtin_amdgcn_mfma_f32_16x16x32_bf16(afr[s], bfr[t], acc[t], 0, 0, 0);
    }

    int rq[4]; bool vq[4];
#pragma unroll
    for (int q = 0; q < 4; ++q) {
        int m = w * 16 + (lane >> 4) * 4 + q;
        vq[q] = m < rows;
        rq[q] = vq[q] ? perm[rowstart + m] : 0;
    }
    const float* bb = bias + bucket * DD;
#pragma unroll
    for (int t = 0; t < 8; ++t) {
        int col = t * 16 + lr;
        float bv = bb[col];
#pragma unroll
        for (int q = 0; q < 4; ++q) {
            if (vq[q]) {
                float v = fmaxf(acc[t][q] + bv, 0.f);
                outr[(size_t)rq[q] * DD + col] = f2bf(v);
            }
        }
    }
}

__global__ __launch_bounds__(256, 2) void mega_kernel(
        const float* __restrict__ emb, const int* __restrict__ pos_ids,
        const int* __restrict__ dep_ids, const float* __restrict__ posW,
        const float* __restrict__ pos_b, const float* __restrict__ depW,
        const float* __restrict__ dep_b, float* __restrict__ out,
        int* __restrict__ meta, int* __restrict__ blk_cnt,
        int* __restrict__ ntiles, int* __restrict__ perm_pos,
        int* __restrict__ perm_dep, int2* __restrict__ tbl1,
        int2* __restrict__ tblL, unsigned short* __restrict__ Wt,
        unsigned short* __restrict__ xbf, unsigned short* __restrict__ uarena) {
    __shared__ __align__(16) char smem[9728];
    int bid = blockIdx.x;
    int tid = threadIdx.x;

    // ---- P0: convert W (blocks 0..255) + per-block hist (blocks 256..426) ----
    if (bid < 256) {
        unsigned short (*lds)[72] = (unsigned short (*)[72])smem;
        int mat = bid >> 2;
        int tile = bid & 3;
        int tk = (tile >> 1) * 64, tn = (tile & 1) * 64;
        const float* W = (mat < NPOS) ? (posW + (size_t)mat * DD * DD)
                                      : (depW + (size_t)(mat - NPOS) * DD * DD);
        unsigned short* O = Wt + (size_t)mat * DD * DD;
        int tx = tid & 63, ty = tid >> 6;
#pragma unroll
        for (int i = 0; i < 16; ++i) {
            int r = ty + i * 4;
            lds[tx][r] = f2bf(W[(size_t)(tk + r) * DD + tn + tx]);
        }
        __syncthreads();
#pragma unroll
        for (int i = 0; i < 16; ++i) {
            int r = ty + i * 4;
            O[(size_t)(tn + r) * DD + tk + tx] = lds[r][tx];
        }
    } else if (bid < 256 + NHB) {
        int* h = (int*)smem;
        for (int i = tid; i < NBUCKET; i += 256) h[i] = 0;
        __syncthreads();
        int hb = bid - 256;
        int g = hb * 256 + tid;
        if (g < NN) {
            atomicAdd(&h[pos_ids[g]], 1);
        } else if (g < NN + NCH) {
            int l, c, b;
            decode_child(g - NN, dep_ids, l, c, b);
            atomicAdd(&h[b], 1);
        }
        __syncthreads();
        for (int i = tid; i < NBUCKET; i += 256)
            blk_cnt[hb * NBUCKET + i] = h[i];
    }
    gridbar(meta, 0);

    // ---- P1: scatter + plan (blocks 0..170); block 0 also builds tbl ----
    if (bid < NHB) {
        int* tot = (int*)smem;             // [340]
        int* pre = tot + NBUCKET;          // [340]
        int* scb = pre + NBUCKET;          // [340]
        int* h   = scb + NBUCKET;          // [340]
        for (int i = tid; i < NBUCKET; i += 256) {
            int sa = 0, sb = 0;
            for (int bb = 0; bb < NHB; ++bb) {
                int v = blk_cnt[bb * NBUCKET + i];
                sa += v;
                if (bb < bid) sb += v;
            }
            tot[i] = sa; pre[i] = sb; h[i] = 0;
        }
        __syncthreads();
        if (tid == 0) {
            const int baseTab[7] = {0, 4, 20, 84, 340, 1364, 5460}; // ls[l+1]-1
            int off = 0;
            for (int i = 0; i < NPOS; ++i) { scb[i] = off; off += tot[i]; }
            for (int l = 0; l < 7; ++l) {
                off = baseTab[l];
                for (int j = 0; j < NDEP; ++j) {
                    int i = NPOS + l * NDEP + j;
                    scb[i] = off; off += tot[i];
                }
            }
        }
        __syncthreads();
        int g = bid * 256 + tid;
        int b = -1, payload = 0;
        if (g < NN) {
            b = pos_ids[g]; payload = g;
        } else if (g < NN + NCH) {
            int l, c;
            decode_child(g - NN, dep_ids, l, c, b);
            payload = c;
        }
        if (b >= 0) {
            int local = atomicAdd(&h[b], 1);
            int idx = scb[b] + pre[b] + local;
            if (b < NPOS) perm_pos[idx] = payload;
            else perm_dep[idx] = payload;
        }
        if (bid == 0 && tid == 0) {
            int t1 = 0;
            for (int i = 0; i < NPOS; ++i) {
                int c = tot[i], base = scb[i];
                for (int rs = 0; rs < c; rs += 64) {
                    int2 ent; ent.x = i | (min(64, c - rs) << 8); ent.y = base + rs;
                    tbl1[t1++] = ent;
                }
            }
            ntiles[0] = t1;
            for (int l = 0; l < 7; ++l) {
                int t = 0;
                for (int j = 0; j < NDEP; ++j) {
                    int i = NPOS + l * NDEP + j;
                    int c = tot[i], base = scb[i];
                    for (int rs = 0; rs < c; rs += 64) {
                        int2 ent; ent.x = j | (min(64, c - rs) << 8); ent.y = base + rs;
                        tblL[l * 302 + t++] = ent;
                    }
                }
                ntiles[1 + l] = t;
            }
        }
    }
    gridbar(meta, 1);

    // u buffer offsets (rows) per level l: U[l] holds 4^(l+1) rows
    // U6:0  U5:16384  U4:20480  U3:21504  U2:21760  U1:21824  U0:21840
    const int uoff[7] = {21840, 21824, 21760, 21504, 20480, 16384, 0};
    const int lsc[7]  = {1, 5, 21, 85, 341, 1365, 5461};   // ls[l+1]

    // ---- P2: stage1 GEMM ----
    if (bid < ntiles[0])
        gemm_tile<0>(tbl1[bid], perm_pos, Wt, pos_b, emb, nullptr, nullptr, xbf);
    gridbar(meta, 2);

    const unsigned short* Wtd = Wt + (size_t)NPOS * DD * DD;
    // ---- P3: level 6 ----
    if (bid < ntiles[7])
        gemm_tile<1>(tblL[6 * 302 + bid], perm_dep, Wtd, dep_b, nullptr,
                     xbf + (size_t)lsc[6] * DD, nullptr,
                     uarena + (size_t)uoff[6] * DD);
    gridbar(meta, 3);

    // ---- P4..P8: levels 5..1 ----
    int baridx = 4;
    for (int l = 5; l >= 1; --l) {
        if (bid < ntiles[1 + l])
            gemm_tile<2>(tblL[l * 302 + bid], perm_dep, Wtd, dep_b, nullptr,
                         xbf + (size_t)lsc[l] * DD,
                         uarena + (size_t)uoff[l + 1] * DD,
                         uarena + (size_t)uoff[l] * DD);
        gridbar(meta, baridx++);
    }

    // ---- P9: level 0 (<=4 tiles, serial in block 0) + final ----
    if (bid == 0) {
        int nt0 = ntiles[1];
        unsigned short* u0 = uarena + (size_t)uoff[0] * DD;
        for (int t = 0; t < nt0; ++t)
            gemm_tile<2>(tblL[0 * 302 + t], perm_dep, Wtd, dep_b, nullptr,
                         xbf + (size_t)lsc[0] * DD,
                         uarena + (size_t)uoff[1] * DD, u0);
        __syncthreads();
        if (tid < DD) {
            unsigned short m = xbf[tid];
#pragma unroll
            for (int j = 0; j < 4; ++j) {
                unsigned short u = u0[j * DD + tid];
                if (u > m) m = u;
            }
            out[tid] = bf2f(m);
        }
    }
}

extern "C" void kernel_launch(void* const* d_in, const int* in_sizes, int n_in,
                              void* d_out, int out_size, void* d_ws, size_t ws_size,
                              hipStream_t stream) {
    const float* emb     = (const float*)d_in[0];
    const int*   pos_ids = (const int*)d_in[1];
    const int*   dep_ids = (const int*)d_in[2];
    const float* pos_W   = (const float*)d_in[3];
    const float* pos_b   = (const float*)d_in[4];
    const float* dep_W   = (const float*)d_in[5];
    const float* dep_b   = (const float*)d_in[6];
    float* out = (float*)d_out;

    char* p = (char*)d_ws;
    auto alloc = [&](size_t bytes) {
        char* r = p; p += (bytes + 255) & ~(size_t)255; return r;
    };
    const int meta_ints = NBAR * 8 * 32 + NBAR * 32 * 3 + 32;   // 3200
    int* meta = (int*)alloc((size_t)meta_ints * 4);
    int* blk_cnt  = (int*)alloc((size_t)NHB * NBUCKET * 4);
    int* ntiles   = (int*)alloc(8 * 4);
    int* perm_pos = (int*)alloc((size_t)NN * 4);
    int* perm_dep = (int*)alloc((size_t)NCH * 4);
    int2* tbl1    = (int2*)alloc(384 * 8);
    int2* tblL    = (int2*)alloc(7 * 302 * 8);
    unsigned short* Wt     = (unsigned short*)alloc((size_t)64 * DD * DD * 2);
    unsigned short* xbf    = (unsigned short*)alloc((size_t)NN * DD * 2);
    unsigned short* uarena = (unsigned short*)alloc((size_t)NCH * DD * 2);

    hipMemsetAsync(meta, 0, (size_t)meta_ints * 4, stream);
    mega_kernel<<<GRID, 256, 0, stream>>>(emb, pos_ids, dep_ids, pos_W, pos_b,
                                          dep_W, dep_b, out, meta, blk_cnt,
                                          ntiles, perm_pos, perm_dep,
                                          tbl1, tblL, Wt, xbf, uarena);
}